// Round 13
// baseline (283.800 us; speedup 1.0000x reference)
//
#include <hip/hip_runtime.h>

#define B_ 16
#define QN 256
#define KN 256
#define DN 256
#define HN 256

#define LOG2E 1.4426950408889634f
#define TWOLOG2E 2.8853900817779268f  // exp2(x*this) = e^{2x}

// ---------------- Kernel A (fused): projections + exp ----------------
// (unchanged: 16 rows/block, 4r x 4h per thread, W 2-stage pipelined,
//  exp2 applied in epilogue; k-path stored transposed in [h/8][k][8] octets)
__global__ __launch_bounds__(256) void proj_kernel(const float* __restrict__ Xq,
                                                   const float* __restrict__ Xk,
                                                   const float* __restrict__ Wq,
                                                   const float* __restrict__ Wk,
                                                   float* __restrict__ EQ,
                                                   float* __restrict__ EKT,
                                                   float scale) {
    const int nb = (int)gridDim.x >> 1;
    int blk = blockIdx.x;
    const bool is_q = blk < nb;
    const float* X;
    const float* W;
    if (is_q) { X = Xq; W = Wq; }
    else      { X = Xk; W = Wk; blk -= nb; }
    const int row0 = blk * 16;

    __shared__ float xl[16][260];
    __shared__ float trans[16][260];
    const int tid = threadIdx.x;

    {
        const float4* src = (const float4*)(X + (size_t)row0 * DN);
#pragma unroll
        for (int i = 0; i < 4; ++i) {
            int idx = tid + 256 * i;
            int r = idx >> 6, c = (idx & 63) << 2;
            *(float4*)&xl[r][c] = src[idx];
        }
    }
    __syncthreads();

    const int rg = tid >> 6;
    const int h4 = (tid & 63) << 2;

    float4 acc[4];
#pragma unroll
    for (int r = 0; r < 4; ++r) acc[r] = make_float4(0.f, 0.f, 0.f, 0.f);

    float4 wb0[4], wb1[4];
#pragma unroll
    for (int j = 0; j < 4; ++j) wb0[j] = *(const float4*)&W[(size_t)j * HN + h4];

#define PROJ_COMP(WB, D0)                                                      \
    do {                                                                       \
        float4 x[4];                                                           \
        _Pragma("unroll") for (int r = 0; r < 4; ++r)                          \
            x[r] = *(const float4*)&xl[(rg << 2) + r][(D0)];                   \
        _Pragma("unroll") for (int r = 0; r < 4; ++r) {                        \
            acc[r].x = fmaf(x[r].x, WB[0].x, acc[r].x);                        \
            acc[r].y = fmaf(x[r].x, WB[0].y, acc[r].y);                        \
            acc[r].z = fmaf(x[r].x, WB[0].z, acc[r].z);                        \
            acc[r].w = fmaf(x[r].x, WB[0].w, acc[r].w);                        \
            acc[r].x = fmaf(x[r].y, WB[1].x, acc[r].x);                        \
            acc[r].y = fmaf(x[r].y, WB[1].y, acc[r].y);                        \
            acc[r].z = fmaf(x[r].y, WB[1].z, acc[r].z);                        \
            acc[r].w = fmaf(x[r].y, WB[1].w, acc[r].w);                        \
            acc[r].x = fmaf(x[r].z, WB[2].x, acc[r].x);                        \
            acc[r].y = fmaf(x[r].z, WB[2].y, acc[r].y);                        \
            acc[r].z = fmaf(x[r].z, WB[2].z, acc[r].z);                        \
            acc[r].w = fmaf(x[r].z, WB[2].w, acc[r].w);                        \
            acc[r].x = fmaf(x[r].w, WB[3].x, acc[r].x);                        \
            acc[r].y = fmaf(x[r].w, WB[3].y, acc[r].y);                        \
            acc[r].z = fmaf(x[r].w, WB[3].z, acc[r].z);                        \
            acc[r].w = fmaf(x[r].w, WB[3].w, acc[r].w);                        \
        }                                                                      \
    } while (0)

    for (int d0 = 0; d0 < DN; d0 += 8) {
#pragma unroll
        for (int j = 0; j < 4; ++j)
            wb1[j] = *(const float4*)&W[(size_t)(d0 + 4 + j) * HN + h4];
        PROJ_COMP(wb0, d0);
        if (d0 + 8 < DN) {
#pragma unroll
            for (int j = 0; j < 4; ++j)
                wb0[j] = *(const float4*)&W[(size_t)(d0 + 8 + j) * HN + h4];
        }
        PROJ_COMP(wb1, d0 + 4);
    }

#pragma unroll
    for (int r = 0; r < 4; ++r) {
        acc[r].x = __builtin_amdgcn_exp2f(acc[r].x * scale);
        acc[r].y = __builtin_amdgcn_exp2f(acc[r].y * scale);
        acc[r].z = __builtin_amdgcn_exp2f(acc[r].z * scale);
        acc[r].w = __builtin_amdgcn_exp2f(acc[r].w * scale);
    }

    if (is_q) {
#pragma unroll
        for (int r = 0; r < 4; ++r)
            *(float4*)&EQ[(size_t)(row0 + (rg << 2) + r) * HN + h4] = acc[r];
    } else {
#pragma unroll
        for (int r = 0; r < 4; ++r)
            *(float4*)&trans[(rg << 2) + r][h4] = acc[r];
        __syncthreads();
        const int b = row0 >> 8, kloc0 = row0 & 255;
        float* dstb = EKT + (size_t)b * 32 * 256 * 8;
#pragma unroll
        for (int i = 0; i < 4; ++i) {
            int idx = i * 256 + tid;
            int u4 = (idx & 1) << 2;
            int kj = (idx >> 1) & 15;
            int h0 = idx >> 5;
            float4 val = *(const float4*)&trans[kj][h0 * 8 + u4];
            *(float4*)&dstb[((size_t)h0 * 256 + kloc0 + kj) * 8 + u4] = val;
        }
    }
}

// ------------- Kernel B (fused): score + masked softmax + PV ----------------
// Grid 1024 flat; b = bid&15 -> bid%8 == b%8 pins each batch's ek/V to one XCD L2
// (R12's FETCH drop: 15.5 -> 3.8 MB). Block = 4 waves, 4 q rows.
// score: wave = k-group (k = 64w+lane) for all 4 q; 4-DEEP k-prefetch (~750 cyc
//   of compute between load issue and use) to cover L3/HBM-miss latency.
// softmax: intra-wave shfl + LDS cross-wave combine; masked p == 0.
// PV: D-SPLIT -- wave w owns d in [64w,64w+64); p exchanged via p_lds[k][q] (4 KB),
//   read back as one b128 broadcast per k; every wave active regardless of len.
__global__ __launch_bounds__(256, 4) void attn_kernel(const float* __restrict__ EQ,
                                                      const float* __restrict__ EKT,
                                                      const float* __restrict__ wv,
                                                      const int* __restrict__ lens,
                                                      const float* __restrict__ V,
                                                      float* __restrict__ OUT) {
    const int bid = blockIdx.x;
    const int b = bid & 15;
    const int q0 = (bid >> 4) * 4;
    const int len = lens[b];

    __shared__ float eq_lds[4][256];    // 4 KB
    __shared__ float wv_lds[256];       // 1 KB
    __shared__ float p_lds[256][4];     // 4 KB, [k][q] for b128 broadcast reads
    __shared__ float maxb[4][4];
    __shared__ float sumb[4][4];

    const int tid = threadIdx.x;
    const int w = tid >> 6, lane = tid & 63;

    {
        const float4* src = (const float4*)&EQ[((size_t)b * QN + q0) * HN];
        ((float4*)&eq_lds[0][0])[tid] = src[tid];   // 4 rows = 256 float4
        if (tid < 64) *(float4*)&wv_lds[tid << 2] = *(const float4*)&wv[tid << 2];
    }
    __syncthreads();

    const bool act = (w * 64) < len;          // wave-uniform
    float acc[4] = {0.f, 0.f, 0.f, 0.f};

#define WINDOW(KA, KB, H8)                                                        \
    do {                                                                          \
        float4 wa = *(const float4*)&wv_lds[(H8)];                                \
        float4 wb = *(const float4*)&wv_lds[(H8) + 4];                            \
        _Pragma("unroll") for (int qq = 0; qq < 4; ++qq) {                        \
            float4 qa = *(const float4*)&eq_lds[qq][(H8)];                        \
            float4 qb = *(const float4*)&eq_lds[qq][(H8) + 4];                    \
            float t = acc[qq];                                                    \
            t = fmaf(wa.x, __builtin_amdgcn_rcpf(fmaf(qa.x, KA.x, 1.f)), t);      \
            t = fmaf(wa.y, __builtin_amdgcn_rcpf(fmaf(qa.y, KA.y, 1.f)), t);      \
            t = fmaf(wa.z, __builtin_amdgcn_rcpf(fmaf(qa.z, KA.z, 1.f)), t);      \
            t = fmaf(wa.w, __builtin_amdgcn_rcpf(fmaf(qa.w, KA.w, 1.f)), t);      \
            t = fmaf(wb.x, __builtin_amdgcn_rcpf(fmaf(qb.x, KB.x, 1.f)), t);      \
            t = fmaf(wb.y, __builtin_amdgcn_rcpf(fmaf(qb.y, KB.y, 1.f)), t);      \
            t = fmaf(wb.z, __builtin_amdgcn_rcpf(fmaf(qb.z, KB.z, 1.f)), t);      \
            t = fmaf(wb.w, __builtin_amdgcn_rcpf(fmaf(qb.w, KB.w, 1.f)), t);      \
            acc[qq] = t;                                                          \
        }                                                                         \
    } while (0)

    if (act) {
        const float* kp = EKT + (size_t)b * (32 * 256 * 8) + (size_t)(w * 64 + lane) * 8;
        float4 ka[4], kb[4];
#pragma unroll
        for (int j = 0; j < 4; ++j) {
            ka[j] = *(const float4*)&kp[(size_t)j * 2048];
            kb[j] = *(const float4*)&kp[(size_t)j * 2048 + 4];
        }
        for (int hw = 0; hw < 32; hw += 4) {
#pragma unroll
            for (int j = 0; j < 4; ++j) {
                WINDOW(ka[j], kb[j], (hw + j) * 8);
                if (hw + 4 + j < 32) {
                    const float* kn = kp + (size_t)(hw + 4 + j) * 2048;
                    ka[j] = *(const float4*)&kn[0];
                    kb[j] = *(const float4*)&kn[4];
                }
            }
        }
    }

    const bool kvalid = (w * 64 + lane) < len;
    float xs0 = kvalid ? (-2.f * acc[0]) : -1e6f;
    float xs1 = kvalid ? (-2.f * acc[1]) : -1e6f;
    float xs2 = kvalid ? (-2.f * acc[2]) : -1e6f;
    float xs3 = kvalid ? (-2.f * acc[3]) : -1e6f;

    float m0 = xs0, m1 = xs1, m2 = xs2, m3 = xs3;
#pragma unroll
    for (int off = 32; off; off >>= 1) {
        m0 = fmaxf(m0, __shfl_xor(m0, off, 64));
        m1 = fmaxf(m1, __shfl_xor(m1, off, 64));
        m2 = fmaxf(m2, __shfl_xor(m2, off, 64));
        m3 = fmaxf(m3, __shfl_xor(m3, off, 64));
    }
    if (lane == 0) {
        maxb[w][0] = m0; maxb[w][1] = m1; maxb[w][2] = m2; maxb[w][3] = m3;
    }
    __syncthreads();
    float g0 = fmaxf(fmaxf(maxb[0][0], maxb[1][0]), fmaxf(maxb[2][0], maxb[3][0]));
    float g1 = fmaxf(fmaxf(maxb[0][1], maxb[1][1]), fmaxf(maxb[2][1], maxb[3][1]));
    float g2 = fmaxf(fmaxf(maxb[0][2], maxb[1][2]), fmaxf(maxb[2][2], maxb[3][2]));
    float g3 = fmaxf(fmaxf(maxb[0][3], maxb[1][3]), fmaxf(maxb[2][3], maxb[3][3]));

    float p0 = __builtin_amdgcn_exp2f((xs0 - g0) * LOG2E);
    float p1 = __builtin_amdgcn_exp2f((xs1 - g1) * LOG2E);
    float p2 = __builtin_amdgcn_exp2f((xs2 - g2) * LOG2E);
    float p3 = __builtin_amdgcn_exp2f((xs3 - g3) * LOG2E);

    float s0 = p0, s1 = p1, s2 = p2, s3 = p3;
#pragma unroll
    for (int off = 32; off; off >>= 1) {
        s0 += __shfl_xor(s0, off, 64);
        s1 += __shfl_xor(s1, off, 64);
        s2 += __shfl_xor(s2, off, 64);
        s3 += __shfl_xor(s3, off, 64);
    }
    if (lane == 0) {
        sumb[w][0] = s0; sumb[w][1] = s1; sumb[w][2] = s2; sumb[w][3] = s3;
    }
    __syncthreads();
    float t0 = (sumb[0][0] + sumb[1][0]) + (sumb[2][0] + sumb[3][0]);
    float t1 = (sumb[0][1] + sumb[1][1]) + (sumb[2][1] + sumb[3][1]);
    float t2 = (sumb[0][2] + sumb[1][2]) + (sumb[2][2] + sumb[3][2]);
    float t3 = (sumb[0][3] + sumb[1][3]) + (sumb[2][3] + sumb[3][3]);
    p0 *= 1.f / t0;
    p1 *= 1.f / t1;
    p2 *= 1.f / t2;
    p3 *= 1.f / t3;

    // exchange p: lane's k-row = 64w+lane; one b128 store per lane (dense)
    *(float4*)&p_lds[w * 64 + lane][0] = make_float4(p0, p1, p2, p3);
    __syncthreads();

    // PV d-split: wave w owns d = 64w + lane; loop all valid k (balanced)
    {
        const int d = (w << 6) + lane;
        const float* vcol = V + (size_t)b * KN * DN + d;
        float o0 = 0.f, o1 = 0.f, o2 = 0.f, o3 = 0.f;
        int k = 0;
        for (; k + 4 <= len; k += 4) {
            float v0 = vcol[(size_t)(k + 0) * DN];
            float v1 = vcol[(size_t)(k + 1) * DN];
            float v2 = vcol[(size_t)(k + 2) * DN];
            float v3 = vcol[(size_t)(k + 3) * DN];
            float4 pa = *(const float4*)&p_lds[k + 0][0];   // broadcast
            float4 pb = *(const float4*)&p_lds[k + 1][0];
            float4 pc = *(const float4*)&p_lds[k + 2][0];
            float4 pd = *(const float4*)&p_lds[k + 3][0];
            o0 = fmaf(pa.x, v0, o0); o1 = fmaf(pa.y, v0, o1);
            o2 = fmaf(pa.z, v0, o2); o3 = fmaf(pa.w, v0, o3);
            o0 = fmaf(pb.x, v1, o0); o1 = fmaf(pb.y, v1, o1);
            o2 = fmaf(pb.z, v1, o2); o3 = fmaf(pb.w, v1, o3);
            o0 = fmaf(pc.x, v2, o0); o1 = fmaf(pc.y, v2, o1);
            o2 = fmaf(pc.z, v2, o2); o3 = fmaf(pc.w, v2, o3);
            o0 = fmaf(pd.x, v3, o0); o1 = fmaf(pd.y, v3, o1);
            o2 = fmaf(pd.z, v3, o2); o3 = fmaf(pd.w, v3, o3);
        }
        for (; k < len; ++k) {
            float v0 = vcol[(size_t)k * DN];
            float4 pa = *(const float4*)&p_lds[k][0];
            o0 = fmaf(pa.x, v0, o0); o1 = fmaf(pa.y, v0, o1);
            o2 = fmaf(pa.z, v0, o2); o3 = fmaf(pa.w, v0, o3);
        }
        float* ob = OUT + ((size_t)b * QN + q0) * DN + d;
        ob[0 * DN] = o0;
        ob[1 * DN] = o1;
        ob[2 * DN] = o2;
        ob[3 * DN] = o3;
    }
}

extern "C" void kernel_launch(void* const* d_in, const int* in_sizes, int n_in,
                              void* d_out, int out_size, void* d_ws, size_t ws_size,
                              hipStream_t stream) {
    const float* queries = (const float*)d_in[0];
    const float* keys    = (const float*)d_in[1];
    const float* values  = (const float*)d_in[2];
    const int*   lens    = (const int*)d_in[3];
    const float* Wq      = (const float*)d_in[4];
    const float* Wk      = (const float*)d_in[5];
    const float* wv      = (const float*)d_in[6];
    float* out = (float*)d_out;

    float* eq  = (float*)d_ws;                       // [B,Q,H]   4 MB (exp'd, row-major)
    float* ekT = eq + (size_t)B_ * QN * HN;          // [B,32,K,8] 4 MB (exp'd, octets)

    proj_kernel<<<(B_ * QN + B_ * KN) / 16, 256, 0, stream>>>(
        queries, keys, Wq, Wk, eq, ekT, TWOLOG2E);

    attn_kernel<<<(QN / 4) * B_, 256, 0, stream>>>(eq, ekT, wv, lens, values, out);
}

// Round 14
// 65.162 us; speedup vs baseline: 4.3553x; 4.3553x over previous
//
#include <hip/hip_runtime.h>

#define B_ 16
#define QN 256
#define KN 256
#define DN 256
#define HN 256

#define LOG2E 1.4426950408889634f
#define TWOLOG2E 2.8853900817779268f  // exp2(x*this) = e^{2x}

__device__ inline float readlane_f(float v, int l) {
    return __uint_as_float(__builtin_amdgcn_readlane(__float_as_uint(v), l));
}

// ---------------- Kernel A (fused): projections + exp ----------------
// (unchanged: 16 rows/block, 4r x 4h per thread, W 2-stage pipelined,
//  exp2 applied in epilogue; k-path stored transposed in [h/8][k][8] octets)
__global__ __launch_bounds__(256) void proj_kernel(const float* __restrict__ Xq,
                                                   const float* __restrict__ Xk,
                                                   const float* __restrict__ Wq,
                                                   const float* __restrict__ Wk,
                                                   float* __restrict__ EQ,
                                                   float* __restrict__ EKT,
                                                   float scale) {
    const int nb = (int)gridDim.x >> 1;
    int blk = blockIdx.x;
    const bool is_q = blk < nb;
    const float* X;
    const float* W;
    if (is_q) { X = Xq; W = Wq; }
    else      { X = Xk; W = Wk; blk -= nb; }
    const int row0 = blk * 16;

    __shared__ float xl[16][260];
    __shared__ float trans[16][260];
    const int tid = threadIdx.x;

    {
        const float4* src = (const float4*)(X + (size_t)row0 * DN);
#pragma unroll
        for (int i = 0; i < 4; ++i) {
            int idx = tid + 256 * i;
            int r = idx >> 6, c = (idx & 63) << 2;
            *(float4*)&xl[r][c] = src[idx];
        }
    }
    __syncthreads();

    const int rg = tid >> 6;
    const int h4 = (tid & 63) << 2;

    float4 acc[4];
#pragma unroll
    for (int r = 0; r < 4; ++r) acc[r] = make_float4(0.f, 0.f, 0.f, 0.f);

    float4 wb0[4], wb1[4];
#pragma unroll
    for (int j = 0; j < 4; ++j) wb0[j] = *(const float4*)&W[(size_t)j * HN + h4];

#define PROJ_COMP(WB, D0)                                                      \
    do {                                                                       \
        float4 x[4];                                                           \
        _Pragma("unroll") for (int r = 0; r < 4; ++r)                          \
            x[r] = *(const float4*)&xl[(rg << 2) + r][(D0)];                   \
        _Pragma("unroll") for (int r = 0; r < 4; ++r) {                        \
            acc[r].x = fmaf(x[r].x, WB[0].x, acc[r].x);                        \
            acc[r].y = fmaf(x[r].x, WB[0].y, acc[r].y);                        \
            acc[r].z = fmaf(x[r].x, WB[0].z, acc[r].z);                        \
            acc[r].w = fmaf(x[r].x, WB[0].w, acc[r].w);                        \
            acc[r].x = fmaf(x[r].y, WB[1].x, acc[r].x);                        \
            acc[r].y = fmaf(x[r].y, WB[1].y, acc[r].y);                        \
            acc[r].z = fmaf(x[r].y, WB[1].z, acc[r].z);                        \
            acc[r].w = fmaf(x[r].y, WB[1].w, acc[r].w);                        \
            acc[r].x = fmaf(x[r].z, WB[2].x, acc[r].x);                        \
            acc[r].y = fmaf(x[r].z, WB[2].y, acc[r].y);                        \
            acc[r].z = fmaf(x[r].z, WB[2].z, acc[r].z);                        \
            acc[r].w = fmaf(x[r].z, WB[2].w, acc[r].w);                        \
            acc[r].x = fmaf(x[r].w, WB[3].x, acc[r].x);                        \
            acc[r].y = fmaf(x[r].w, WB[3].y, acc[r].y);                        \
            acc[r].z = fmaf(x[r].w, WB[3].z, acc[r].z);                        \
            acc[r].w = fmaf(x[r].w, WB[3].w, acc[r].w);                        \
        }                                                                      \
    } while (0)

    for (int d0 = 0; d0 < DN; d0 += 8) {
#pragma unroll
        for (int j = 0; j < 4; ++j)
            wb1[j] = *(const float4*)&W[(size_t)(d0 + 4 + j) * HN + h4];
        PROJ_COMP(wb0, d0);
        if (d0 + 8 < DN) {
#pragma unroll
            for (int j = 0; j < 4; ++j)
                wb0[j] = *(const float4*)&W[(size_t)(d0 + 8 + j) * HN + h4];
        }
        PROJ_COMP(wb1, d0 + 4);
    }

#pragma unroll
    for (int r = 0; r < 4; ++r) {
        acc[r].x = __builtin_amdgcn_exp2f(acc[r].x * scale);
        acc[r].y = __builtin_amdgcn_exp2f(acc[r].y * scale);
        acc[r].z = __builtin_amdgcn_exp2f(acc[r].z * scale);
        acc[r].w = __builtin_amdgcn_exp2f(acc[r].w * scale);
    }

    if (is_q) {
#pragma unroll
        for (int r = 0; r < 4; ++r)
            *(float4*)&EQ[(size_t)(row0 + (rg << 2) + r) * HN + h4] = acc[r];
    } else {
#pragma unroll
        for (int r = 0; r < 4; ++r)
            *(float4*)&trans[(rg << 2) + r][h4] = acc[r];
        __syncthreads();
        const int b = row0 >> 8, kloc0 = row0 & 255;
        float* dstb = EKT + (size_t)b * 32 * 256 * 8;
#pragma unroll
        for (int i = 0; i < 4; ++i) {
            int idx = i * 256 + tid;
            int u4 = (idx & 1) << 2;
            int kj = (idx >> 1) & 15;
            int h0 = idx >> 5;
            float4 val = *(const float4*)&trans[kj][h0 * 8 + u4];
            *(float4*)&dstb[((size_t)h0 * 256 + kloc0 + kj) * 8 + u4] = val;
        }
    }
}

// ------------- Kernel B (fused): score + masked softmax + PV ----------------
// R11 structure (proven 41 us) + XCD pinning ONLY: flat grid, b = bid&15 so
// bid%8 == b&7 pins each batch's ek/V/eq to one XCD L2 (R12: FETCH 15.5->3.8 MB).
// Block = 4 waves = 4 q rows; wave = one k-group (k = 64w+lane) for all 4 q.
// q/wv in LDS (b128 broadcasts); k loads 2-deep pipelined with NAMED registers
// (arrays spill to scratch -- R13 lesson); PV 4-deep batched; LDS O-reduce.
__global__ __launch_bounds__(256, 4) void attn_kernel(const float* __restrict__ EQ,
                                                      const float* __restrict__ EKT,
                                                      const float* __restrict__ wv,
                                                      const int* __restrict__ lens,
                                                      const float* __restrict__ V,
                                                      float* __restrict__ OUT) {
    const int bid = blockIdx.x;
    const int b = bid & 15;
    const int q0 = (bid >> 4) * 4;
    const int len = lens[b];

    __shared__ float eq_lds[4][256];    // 4 KB
    __shared__ float wv_lds[256];       // 1 KB
    __shared__ float part[4][4][256];   // 16 KB
    __shared__ float maxb[4][4];
    __shared__ float sumb[4][4];

    const int tid = threadIdx.x;
    const int w = tid >> 6, lane = tid & 63;

    {
        const float4* src = (const float4*)&EQ[((size_t)b * QN + q0) * HN];
        ((float4*)&eq_lds[0][0])[tid] = src[tid];   // 4 rows = 256 float4
        if (tid < 64) *(float4*)&wv_lds[tid << 2] = *(const float4*)&wv[tid << 2];
    }
    __syncthreads();

    const bool act = (w * 64) < len;          // wave-uniform
    float acc[4] = {0.f, 0.f, 0.f, 0.f};

#define WINDOW(KA, KB, H8)                                                        \
    do {                                                                          \
        float4 wa = *(const float4*)&wv_lds[(H8)];                                \
        float4 wb = *(const float4*)&wv_lds[(H8) + 4];                            \
        _Pragma("unroll") for (int qq = 0; qq < 4; ++qq) {                        \
            float4 qa = *(const float4*)&eq_lds[qq][(H8)];                        \
            float4 qb = *(const float4*)&eq_lds[qq][(H8) + 4];                    \
            float t = acc[qq];                                                    \
            t = fmaf(wa.x, __builtin_amdgcn_rcpf(fmaf(qa.x, KA.x, 1.f)), t);      \
            t = fmaf(wa.y, __builtin_amdgcn_rcpf(fmaf(qa.y, KA.y, 1.f)), t);      \
            t = fmaf(wa.z, __builtin_amdgcn_rcpf(fmaf(qa.z, KA.z, 1.f)), t);      \
            t = fmaf(wa.w, __builtin_amdgcn_rcpf(fmaf(qa.w, KA.w, 1.f)), t);      \
            t = fmaf(wb.x, __builtin_amdgcn_rcpf(fmaf(qb.x, KB.x, 1.f)), t);      \
            t = fmaf(wb.y, __builtin_amdgcn_rcpf(fmaf(qb.y, KB.y, 1.f)), t);      \
            t = fmaf(wb.z, __builtin_amdgcn_rcpf(fmaf(qb.z, KB.z, 1.f)), t);      \
            t = fmaf(wb.w, __builtin_amdgcn_rcpf(fmaf(qb.w, KB.w, 1.f)), t);      \
            acc[qq] = t;                                                          \
        }                                                                         \
    } while (0)

    if (act) {
        const float* kp = EKT + (size_t)b * (32 * 256 * 8) + (size_t)(w * 64 + lane) * 8;
        float4 ka0 = *(const float4*)&kp[0];
        float4 kb0 = *(const float4*)&kp[4];
        float4 ka1, kb1;
        for (int hw = 0; hw < 32; hw += 2) {
            const float* kp1 = kp + (size_t)(hw + 1) * 2048;
            ka1 = *(const float4*)&kp1[0];
            kb1 = *(const float4*)&kp1[4];
            WINDOW(ka0, kb0, hw * 8);
            if (hw + 2 < 32) {
                const float* kp2 = kp + (size_t)(hw + 2) * 2048;
                ka0 = *(const float4*)&kp2[0];
                kb0 = *(const float4*)&kp2[4];
            }
            WINDOW(ka1, kb1, hw * 8 + 8);
        }
    }

    const bool kvalid = (w * 64 + lane) < len;
    float xs0 = kvalid ? (-2.f * acc[0]) : -1e6f;
    float xs1 = kvalid ? (-2.f * acc[1]) : -1e6f;
    float xs2 = kvalid ? (-2.f * acc[2]) : -1e6f;
    float xs3 = kvalid ? (-2.f * acc[3]) : -1e6f;

    float m0 = xs0, m1 = xs1, m2 = xs2, m3 = xs3;
#pragma unroll
    for (int off = 32; off; off >>= 1) {
        m0 = fmaxf(m0, __shfl_xor(m0, off, 64));
        m1 = fmaxf(m1, __shfl_xor(m1, off, 64));
        m2 = fmaxf(m2, __shfl_xor(m2, off, 64));
        m3 = fmaxf(m3, __shfl_xor(m3, off, 64));
    }
    if (lane == 0) {
        maxb[w][0] = m0; maxb[w][1] = m1; maxb[w][2] = m2; maxb[w][3] = m3;
    }
    __syncthreads();
    float g0 = fmaxf(fmaxf(maxb[0][0], maxb[1][0]), fmaxf(maxb[2][0], maxb[3][0]));
    float g1 = fmaxf(fmaxf(maxb[0][1], maxb[1][1]), fmaxf(maxb[2][1], maxb[3][1]));
    float g2 = fmaxf(fmaxf(maxb[0][2], maxb[1][2]), fmaxf(maxb[2][2], maxb[3][2]));
    float g3 = fmaxf(fmaxf(maxb[0][3], maxb[1][3]), fmaxf(maxb[2][3], maxb[3][3]));

    float p0 = __builtin_amdgcn_exp2f((xs0 - g0) * LOG2E);
    float p1 = __builtin_amdgcn_exp2f((xs1 - g1) * LOG2E);
    float p2 = __builtin_amdgcn_exp2f((xs2 - g2) * LOG2E);
    float p3 = __builtin_amdgcn_exp2f((xs3 - g3) * LOG2E);

    float s0 = p0, s1 = p1, s2 = p2, s3 = p3;
#pragma unroll
    for (int off = 32; off; off >>= 1) {
        s0 += __shfl_xor(s0, off, 64);
        s1 += __shfl_xor(s1, off, 64);
        s2 += __shfl_xor(s2, off, 64);
        s3 += __shfl_xor(s3, off, 64);
    }
    if (lane == 0) {
        sumb[w][0] = s0; sumb[w][1] = s1; sumb[w][2] = s2; sumb[w][3] = s3;
    }
    __syncthreads();
    float t0 = (sumb[0][0] + sumb[1][0]) + (sumb[2][0] + sumb[3][0]);
    float t1 = (sumb[0][1] + sumb[1][1]) + (sumb[2][1] + sumb[3][1]);
    float t2 = (sumb[0][2] + sumb[1][2]) + (sumb[2][2] + sumb[3][2]);
    float t3 = (sumb[0][3] + sumb[1][3]) + (sumb[2][3] + sumb[3][3]);
    p0 *= 1.f / t0;
    p1 *= 1.f / t1;
    p2 *= 1.f / t2;
    p3 *= 1.f / t3;

    // PV: wave w covers its 64 k rows (clamped to len); 4-deep batched V loads
    float4 op0 = make_float4(0.f, 0.f, 0.f, 0.f);
    float4 op1 = op0, op2 = op0, op3 = op0;
    if (act) {
        int kmax = len - w * 64;
        if (kmax > 64) kmax = 64;
        const float* vb = V + ((size_t)b * KN + (size_t)w * 64) * DN + (lane << 2);

#define PV_STEP(KK, VV)                                                        \
    do {                                                                       \
        float b0 = readlane_f(p0, (KK));                                       \
        float b1 = readlane_f(p1, (KK));                                       \
        float b2 = readlane_f(p2, (KK));                                       \
        float b3 = readlane_f(p3, (KK));                                       \
        op0.x = fmaf(b0, VV.x, op0.x); op0.y = fmaf(b0, VV.y, op0.y);          \
        op0.z = fmaf(b0, VV.z, op0.z); op0.w = fmaf(b0, VV.w, op0.w);          \
        op1.x = fmaf(b1, VV.x, op1.x); op1.y = fmaf(b1, VV.y, op1.y);          \
        op1.z = fmaf(b1, VV.z, op1.z); op1.w = fmaf(b1, VV.w, op1.w);          \
        op2.x = fmaf(b2, VV.x, op2.x); op2.y = fmaf(b2, VV.y, op2.y);          \
        op2.z = fmaf(b2, VV.z, op2.z); op2.w = fmaf(b2, VV.w, op2.w);          \
        op3.x = fmaf(b3, VV.x, op3.x); op3.y = fmaf(b3, VV.y, op3.y);          \
        op3.z = fmaf(b3, VV.z, op3.z); op3.w = fmaf(b3, VV.w, op3.w);          \
    } while (0)

        int kk = 0;
        for (; kk + 4 <= kmax; kk += 4) {
            float4 v0 = *(const float4*)&vb[(size_t)(kk + 0) * DN];
            float4 v1 = *(const float4*)&vb[(size_t)(kk + 1) * DN];
            float4 v2 = *(const float4*)&vb[(size_t)(kk + 2) * DN];
            float4 v3 = *(const float4*)&vb[(size_t)(kk + 3) * DN];
            PV_STEP(kk + 0, v0);
            PV_STEP(kk + 1, v1);
            PV_STEP(kk + 2, v2);
            PV_STEP(kk + 3, v3);
        }
        for (; kk < kmax; ++kk) {
            float4 v0 = *(const float4*)&vb[(size_t)kk * DN];
            PV_STEP(kk, v0);
        }
    }
    {
        const int d4 = lane << 2;
        *(float4*)&part[w][0][d4] = op0;
        *(float4*)&part[w][1][d4] = op1;
        *(float4*)&part[w][2][d4] = op2;
        *(float4*)&part[w][3][d4] = op3;
    }
    __syncthreads();

    {
        const int q = tid >> 6, ln = tid & 63;
        const int d4 = ln << 2;
        float4 r0 = *(const float4*)&part[0][q][d4];
        float4 r1 = *(const float4*)&part[1][q][d4];
        float4 r2 = *(const float4*)&part[2][q][d4];
        float4 r3 = *(const float4*)&part[3][q][d4];
        float4 r = make_float4((r0.x + r1.x) + (r2.x + r3.x),
                               (r0.y + r1.y) + (r2.y + r3.y),
                               (r0.z + r1.z) + (r2.z + r3.z),
                               (r0.w + r1.w) + (r2.w + r3.w));
        *(float4*)&OUT[((size_t)b * QN + q0 + q) * DN + d4] = r;
    }
}

extern "C" void kernel_launch(void* const* d_in, const int* in_sizes, int n_in,
                              void* d_out, int out_size, void* d_ws, size_t ws_size,
                              hipStream_t stream) {
    const float* queries = (const float*)d_in[0];
    const float* keys    = (const float*)d_in[1];
    const float* values  = (const float*)d_in[2];
    const int*   lens    = (const int*)d_in[3];
    const float* Wq      = (const float*)d_in[4];
    const float* Wk      = (const float*)d_in[5];
    const float* wv      = (const float*)d_in[6];
    float* out = (float*)d_out;

    float* eq  = (float*)d_ws;                       // [B,Q,H]   4 MB (exp'd, row-major)
    float* ekT = eq + (size_t)B_ * QN * HN;          // [B,32,K,8] 4 MB (exp'd, octets)

    proj_kernel<<<(B_ * QN + B_ * KN) / 16, 256, 0, stream>>>(
        queries, keys, Wq, Wk, eq, ekT, TWOLOG2E);

    attn_kernel<<<(QN / 4) * B_, 256, 0, stream>>>(eq, ekT, wv, lens, values, out);
}

// Round 15
// 63.258 us; speedup vs baseline: 4.4864x; 1.0301x over previous
//
#include <hip/hip_runtime.h>

#define B_ 16
#define QN 256
#define KN 256
#define DN 256
#define HN 256

#define LOG2E 1.4426950408889634f
#define TWOLOG2E 2.8853900817779268f  // exp2(x*this) = e^{2x}

__device__ inline float readlane_f(float v, int l) {
    return __uint_as_float(__builtin_amdgcn_readlane(__float_as_uint(v), l));
}

// ---------------- Kernel A (fused): projections + exp ----------------
// 16 rows/block; thread = 4 rows x 4 h. Fully software-pipelined:
// W = 4-stage prefetch (lead ~3 sub-steps ~380 cyc > L2 latency),
// x(LDS) = 2-stage prefetch (lead ~128 cyc > LDS latency). All staging in
// named/static-index registers; last 16-d iteration peeled (no conditional loads).
// Outputs are EXPONENTIALS: eq = exp2(s*q@Wq), ek = exp2(s*k@Wk), s = 2*log2(e).
// k-path stored transposed in [h/8][k][8] octets via LDS.
__global__ __launch_bounds__(256, 2) void proj_kernel(const float* __restrict__ Xq,
                                                      const float* __restrict__ Xk,
                                                      const float* __restrict__ Wq,
                                                      const float* __restrict__ Wk,
                                                      float* __restrict__ EQ,
                                                      float* __restrict__ EKT,
                                                      float scale) {
    const int nb = (int)gridDim.x >> 1;
    int blk = blockIdx.x;
    const bool is_q = blk < nb;
    const float* X;
    const float* W;
    if (is_q) { X = Xq; W = Wq; }
    else      { X = Xk; W = Wk; blk -= nb; }
    const int row0 = blk * 16;

    __shared__ float xl[16][260];
    __shared__ float trans[16][260];
    const int tid = threadIdx.x;

    {
        const float4* src = (const float4*)(X + (size_t)row0 * DN);
#pragma unroll
        for (int i = 0; i < 4; ++i) {
            int idx = tid + 256 * i;
            int r = idx >> 6, c = (idx & 63) << 2;
            *(float4*)&xl[r][c] = src[idx];
        }
    }
    __syncthreads();

    const int rg = tid >> 6;          // wave id: rows rg*4 .. rg*4+3
    const int h4 = (tid & 63) << 2;   // 4 h columns

    float4 acc[4];
#pragma unroll
    for (int r = 0; r < 4; ++r) acc[r] = make_float4(0.f, 0.f, 0.f, 0.f);

#define LOADW(WS, D0)                                                          \
    do {                                                                       \
        _Pragma("unroll") for (int j = 0; j < 4; ++j)                          \
            WS[j] = *(const float4*)&W[(size_t)((D0) + j) * HN + h4];          \
    } while (0)

#define LOADX(XS, D0)                                                          \
    do {                                                                       \
        _Pragma("unroll") for (int r = 0; r < 4; ++r)                          \
            XS[r] = *(const float4*)&xl[(rg << 2) + r][(D0)];                  \
    } while (0)

#define COMP(WS, XS)                                                           \
    do {                                                                       \
        _Pragma("unroll") for (int r = 0; r < 4; ++r) {                        \
            acc[r].x = fmaf(XS[r].x, WS[0].x, acc[r].x);                       \
            acc[r].y = fmaf(XS[r].x, WS[0].y, acc[r].y);                       \
            acc[r].z = fmaf(XS[r].x, WS[0].z, acc[r].z);                       \
            acc[r].w = fmaf(XS[r].x, WS[0].w, acc[r].w);                       \
            acc[r].x = fmaf(XS[r].y, WS[1].x, acc[r].x);                       \
            acc[r].y = fmaf(XS[r].y, WS[1].y, acc[r].y);                       \
            acc[r].z = fmaf(XS[r].y, WS[1].z, acc[r].z);                       \
            acc[r].w = fmaf(XS[r].y, WS[1].w, acc[r].w);                       \
            acc[r].x = fmaf(XS[r].z, WS[2].x, acc[r].x);                       \
            acc[r].y = fmaf(XS[r].z, WS[2].y, acc[r].y);                       \
            acc[r].z = fmaf(XS[r].z, WS[2].z, acc[r].z);                       \
            acc[r].w = fmaf(XS[r].z, WS[2].w, acc[r].w);                       \
            acc[r].x = fmaf(XS[r].w, WS[3].x, acc[r].x);                       \
            acc[r].y = fmaf(XS[r].w, WS[3].y, acc[r].y);                       \
            acc[r].z = fmaf(XS[r].w, WS[3].z, acc[r].z);                       \
            acc[r].w = fmaf(XS[r].w, WS[3].w, acc[r].w);                       \
        }                                                                      \
    } while (0)

    {
        float4 w0[4], w1[4], w2[4], w3[4];   // static-index only
        float4 xA[4], xB[4];
        LOADX(xA, 0);
        LOADX(xB, 4);
        LOADW(w0, 0);
        LOADW(w1, 4);
        LOADW(w2, 8);
        LOADW(w3, 12);
        for (int d0 = 0; d0 < DN - 16; d0 += 16) {
            COMP(w0, xA); LOADX(xA, d0 + 8);  LOADW(w0, d0 + 16);
            COMP(w1, xB); LOADX(xB, d0 + 12); LOADW(w1, d0 + 20);
            COMP(w2, xA); LOADX(xA, d0 + 16); LOADW(w2, d0 + 24);
            COMP(w3, xB); LOADX(xB, d0 + 20); LOADW(w3, d0 + 28);
        }
        // peeled epilogue: d0 = 240
        COMP(w0, xA); LOADX(xA, 248);
        COMP(w1, xB); LOADX(xB, 252);
        COMP(w2, xA);
        COMP(w3, xB);
    }

    // apply exp2(scale * acc)
#pragma unroll
    for (int r = 0; r < 4; ++r) {
        acc[r].x = __builtin_amdgcn_exp2f(acc[r].x * scale);
        acc[r].y = __builtin_amdgcn_exp2f(acc[r].y * scale);
        acc[r].z = __builtin_amdgcn_exp2f(acc[r].z * scale);
        acc[r].w = __builtin_amdgcn_exp2f(acc[r].w * scale);
    }

    if (is_q) {
#pragma unroll
        for (int r = 0; r < 4; ++r)
            *(float4*)&EQ[(size_t)(row0 + (rg << 2) + r) * HN + h4] = acc[r];
    } else {
#pragma unroll
        for (int r = 0; r < 4; ++r)
            *(float4*)&trans[(rg << 2) + r][h4] = acc[r];
        __syncthreads();
        const int b = row0 >> 8, kloc0 = row0 & 255;
        float* dstb = EKT + (size_t)b * 32 * 256 * 8;
#pragma unroll
        for (int i = 0; i < 4; ++i) {
            int idx = i * 256 + tid;
            int u4 = (idx & 1) << 2;
            int kj = (idx >> 1) & 15;
            int h0 = idx >> 5;
            float4 val = *(const float4*)&trans[kj][h0 * 8 + u4];
            *(float4*)&dstb[((size_t)h0 * 256 + kloc0 + kj) * 8 + u4] = val;
        }
    }
}

// ------------- Kernel B (fused): score + masked softmax + PV ----------------
// R11 2D grid (b = blockIdx.y): each CU's 4 resident blocks span 4 DIFFERENT
// batches -> len-balanced (R14's batch-pinned mapping was a straggler trap).
// Block = 4 waves = 4 q rows; wave = one k-group (k = 64w+lane) for all 4 q.
// q/wv in LDS (b128 broadcasts); k loads 4-DEEP pipelined in NAMED registers
// (lead ~3 windows, covers any L2/L3/HBM latency; last iteration peeled);
// PV 4-deep batched; LDS O-reduce.
__global__ __launch_bounds__(256, 4) void attn_kernel(const float* __restrict__ EQ,
                                                      const float* __restrict__ EKT,
                                                      const float* __restrict__ wv,
                                                      const int* __restrict__ lens,
                                                      const float* __restrict__ V,
                                                      float* __restrict__ OUT) {
    const int b = blockIdx.y;
    const int q0 = blockIdx.x * 4;
    const int len = lens[b];

    __shared__ float eq_lds[4][256];    // 4 KB
    __shared__ float wv_lds[256];       // 1 KB
    __shared__ float part[4][4][256];   // 16 KB
    __shared__ float maxb[4][4];
    __shared__ float sumb[4][4];

    const int tid = threadIdx.x;
    const int w = tid >> 6, lane = tid & 63;

    {
        const float4* src = (const float4*)&EQ[((size_t)b * QN + q0) * HN];
        ((float4*)&eq_lds[0][0])[tid] = src[tid];   // 4 rows = 256 float4
        if (tid < 64) *(float4*)&wv_lds[tid << 2] = *(const float4*)&wv[tid << 2];
    }
    __syncthreads();

    const bool act = (w * 64) < len;          // wave-uniform
    float acc[4] = {0.f, 0.f, 0.f, 0.f};

#define WINDOW(KA, KB, H8)                                                        \
    do {                                                                          \
        float4 wa = *(const float4*)&wv_lds[(H8)];                                \
        float4 wb = *(const float4*)&wv_lds[(H8) + 4];                            \
        _Pragma("unroll") for (int qq = 0; qq < 4; ++qq) {                        \
            float4 qa = *(const float4*)&eq_lds[qq][(H8)];                        \
            float4 qb = *(const float4*)&eq_lds[qq][(H8) + 4];                    \
            float t = acc[qq];                                                    \
            t = fmaf(wa.x, __builtin_amdgcn_rcpf(fmaf(qa.x, KA.x, 1.f)), t);      \
            t = fmaf(wa.y, __builtin_amdgcn_rcpf(fmaf(qa.y, KA.y, 1.f)), t);      \
            t = fmaf(wa.z, __builtin_amdgcn_rcpf(fmaf(qa.z, KA.z, 1.f)), t);      \
            t = fmaf(wa.w, __builtin_amdgcn_rcpf(fmaf(qa.w, KA.w, 1.f)), t);      \
            t = fmaf(wb.x, __builtin_amdgcn_rcpf(fmaf(qb.x, KB.x, 1.f)), t);      \
            t = fmaf(wb.y, __builtin_amdgcn_rcpf(fmaf(qb.y, KB.y, 1.f)), t);      \
            t = fmaf(wb.z, __builtin_amdgcn_rcpf(fmaf(qb.z, KB.z, 1.f)), t);      \
            t = fmaf(wb.w, __builtin_amdgcn_rcpf(fmaf(qb.w, KB.w, 1.f)), t);      \
            acc[qq] = t;                                                          \
        }                                                                         \
    } while (0)

    if (act) {
        const float* kp = EKT + (size_t)b * (32 * 256 * 8) + (size_t)(w * 64 + lane) * 8;
        float4 ka0 = *(const float4*)&kp[0];
        float4 kb0 = *(const float4*)&kp[4];
        float4 ka1 = *(const float4*)&kp[2048];
        float4 kb1 = *(const float4*)&kp[2048 + 4];
        float4 ka2 = *(const float4*)&kp[4096];
        float4 kb2 = *(const float4*)&kp[4096 + 4];
        float4 ka3 = *(const float4*)&kp[6144];
        float4 kb3 = *(const float4*)&kp[6144 + 4];
        for (int hw = 0; hw < 28; hw += 4) {
            const float* kn = kp + (size_t)(hw + 4) * 2048;
            WINDOW(ka0, kb0, hw * 8);
            ka0 = *(const float4*)&kn[0];
            kb0 = *(const float4*)&kn[4];
            WINDOW(ka1, kb1, (hw + 1) * 8);
            ka1 = *(const float4*)&kn[2048];
            kb1 = *(const float4*)&kn[2048 + 4];
            WINDOW(ka2, kb2, (hw + 2) * 8);
            ka2 = *(const float4*)&kn[4096];
            kb2 = *(const float4*)&kn[4096 + 4];
            WINDOW(ka3, kb3, (hw + 3) * 8);
            ka3 = *(const float4*)&kn[6144];
            kb3 = *(const float4*)&kn[6144 + 4];
        }
        // peeled last group: hw = 28..31
        WINDOW(ka0, kb0, 28 * 8);
        WINDOW(ka1, kb1, 29 * 8);
        WINDOW(ka2, kb2, 30 * 8);
        WINDOW(ka3, kb3, 31 * 8);
    }

    const bool kvalid = (w * 64 + lane) < len;
    float xs0 = kvalid ? (-2.f * acc[0]) : -1e6f;
    float xs1 = kvalid ? (-2.f * acc[1]) : -1e6f;
    float xs2 = kvalid ? (-2.f * acc[2]) : -1e6f;
    float xs3 = kvalid ? (-2.f * acc[3]) : -1e6f;

    float m0 = xs0, m1 = xs1, m2 = xs2, m3 = xs3;
#pragma unroll
    for (int off = 32; off; off >>= 1) {
        m0 = fmaxf(m0, __shfl_xor(m0, off, 64));
        m1 = fmaxf(m1, __shfl_xor(m1, off, 64));
        m2 = fmaxf(m2, __shfl_xor(m2, off, 64));
        m3 = fmaxf(m3, __shfl_xor(m3, off, 64));
    }
    if (lane == 0) {
        maxb[w][0] = m0; maxb[w][1] = m1; maxb[w][2] = m2; maxb[w][3] = m3;
    }
    __syncthreads();
    float g0 = fmaxf(fmaxf(maxb[0][0], maxb[1][0]), fmaxf(maxb[2][0], maxb[3][0]));
    float g1 = fmaxf(fmaxf(maxb[0][1], maxb[1][1]), fmaxf(maxb[2][1], maxb[3][1]));
    float g2 = fmaxf(fmaxf(maxb[0][2], maxb[1][2]), fmaxf(maxb[2][2], maxb[3][2]));
    float g3 = fmaxf(fmaxf(maxb[0][3], maxb[1][3]), fmaxf(maxb[2][3], maxb[3][3]));

    float p0 = __builtin_amdgcn_exp2f((xs0 - g0) * LOG2E);
    float p1 = __builtin_amdgcn_exp2f((xs1 - g1) * LOG2E);
    float p2 = __builtin_amdgcn_exp2f((xs2 - g2) * LOG2E);
    float p3 = __builtin_amdgcn_exp2f((xs3 - g3) * LOG2E);

    float s0 = p0, s1 = p1, s2 = p2, s3 = p3;
#pragma unroll
    for (int off = 32; off; off >>= 1) {
        s0 += __shfl_xor(s0, off, 64);
        s1 += __shfl_xor(s1, off, 64);
        s2 += __shfl_xor(s2, off, 64);
        s3 += __shfl_xor(s3, off, 64);
    }
    if (lane == 0) {
        sumb[w][0] = s0; sumb[w][1] = s1; sumb[w][2] = s2; sumb[w][3] = s3;
    }
    __syncthreads();
    float t0 = (sumb[0][0] + sumb[1][0]) + (sumb[2][0] + sumb[3][0]);
    float t1 = (sumb[0][1] + sumb[1][1]) + (sumb[2][1] + sumb[3][1]);
    float t2 = (sumb[0][2] + sumb[1][2]) + (sumb[2][2] + sumb[3][2]);
    float t3 = (sumb[0][3] + sumb[1][3]) + (sumb[2][3] + sumb[3][3]);
    p0 *= 1.f / t0;
    p1 *= 1.f / t1;
    p2 *= 1.f / t2;
    p3 *= 1.f / t3;

    // PV: wave w covers its 64 k rows (clamped to len); 4-deep batched V loads
    float4 op0 = make_float4(0.f, 0.f, 0.f, 0.f);
    float4 op1 = op0, op2 = op0, op3 = op0;
    if (act) {
        int kmax = len - w * 64;
        if (kmax > 64) kmax = 64;
        const float* vb = V + ((size_t)b * KN + (size_t)w * 64) * DN + (lane << 2);

#define PV_STEP(KK, VV)                                                        \
    do {                                                                       \
        float b0 = readlane_f(p0, (KK));                                       \
        float b1 = readlane_f(p1, (KK));                                       \
        float b2 = readlane_f(p2, (KK));                                       \
        float b3 = readlane_f(p3, (KK));                                       \
        op0.x = fmaf(b0, VV.x, op0.x); op0.y = fmaf(b0, VV.y, op0.y);          \
        op0.z = fmaf(b0, VV.z, op0.z); op0.w = fmaf(b0, VV.w, op0.w);          \
        op1.x = fmaf(b1, VV.x, op1.x); op1.y = fmaf(b1, VV.y, op1.y);          \
        op1.z = fmaf(b1, VV.z, op1.z); op1.w = fmaf(b1, VV.w, op1.w);          \
        op2.x = fmaf(b2, VV.x, op2.x); op2.y = fmaf(b2, VV.y, op2.y);          \
        op2.z = fmaf(b2, VV.z, op2.z); op2.w = fmaf(b2, VV.w, op2.w);          \
        op3.x = fmaf(b3, VV.x, op3.x); op3.y = fmaf(b3, VV.y, op3.y);          \
        op3.z = fmaf(b3, VV.z, op3.z); op3.w = fmaf(b3, VV.w, op3.w);          \
    } while (0)

        int kk = 0;
        for (; kk + 4 <= kmax; kk += 4) {
            float4 v0 = *(const float4*)&vb[(size_t)(kk + 0) * DN];
            float4 v1 = *(const float4*)&vb[(size_t)(kk + 1) * DN];
            float4 v2 = *(const float4*)&vb[(size_t)(kk + 2) * DN];
            float4 v3 = *(const float4*)&vb[(size_t)(kk + 3) * DN];
            PV_STEP(kk + 0, v0);
            PV_STEP(kk + 1, v1);
            PV_STEP(kk + 2, v2);
            PV_STEP(kk + 3, v3);
        }
        for (; kk < kmax; ++kk) {
            float4 v0 = *(const float4*)&vb[(size_t)kk * DN];
            PV_STEP(kk, v0);
        }
    }
    {
        const int d4 = lane << 2;
        *(float4*)&part[w][0][d4] = op0;
        *(float4*)&part[w][1][d4] = op1;
        *(float4*)&part[w][2][d4] = op2;
        *(float4*)&part[w][3][d4] = op3;
    }
    __syncthreads();

    {
        const int q = tid >> 6, ln = tid & 63;
        const int d4 = ln << 2;
        float4 r0 = *(const float4*)&part[0][q][d4];
        float4 r1 = *(const float4*)&part[1][q][d4];
        float4 r2 = *(const float4*)&part[2][q][d4];
        float4 r3 = *(const float4*)&part[3][q][d4];
        float4 r = make_float4((r0.x + r1.x) + (r2.x + r3.x),
                               (r0.y + r1.y) + (r2.y + r3.y),
                               (r0.z + r1.z) + (r2.z + r3.z),
                               (r0.w + r1.w) + (r2.w + r3.w));
        *(float4*)&OUT[((size_t)b * QN + q0 + q) * DN + d4] = r;
    }
}

extern "C" void kernel_launch(void* const* d_in, const int* in_sizes, int n_in,
                              void* d_out, int out_size, void* d_ws, size_t ws_size,
                              hipStream_t stream) {
    const float* queries = (const float*)d_in[0];
    const float* keys    = (const float*)d_in[1];
    const float* values  = (const float*)d_in[2];
    const int*   lens    = (const int*)d_in[3];
    const float* Wq      = (const float*)d_in[4];
    const float* Wk      = (const float*)d_in[5];
    const float* wv      = (const float*)d_in[6];
    float* out = (float*)d_out;

    float* eq  = (float*)d_ws;                       // [B,Q,H]   4 MB (exp'd, row-major)
    float* ekT = eq + (size_t)B_ * QN * HN;          // [B,32,K,8] 4 MB (exp'd, octets)

    proj_kernel<<<(B_ * QN + B_ * KN) / 16, 256, 0, stream>>>(
        queries, keys, Wq, Wk, eq, ekT, TWOLOG2E);

    dim3 gB(QN / 4, B_);
    attn_kernel<<<gB, 256, 0, stream>>>(eq, ekT, wv, lens, values, out);
}

// Round 16
// 56.279 us; speedup vs baseline: 5.0427x; 1.1240x over previous
//
#include <hip/hip_runtime.h>

#define B_ 16
#define QN 256
#define KN 256
#define DN 256
#define HN 256

#define LOG2E 1.4426950408889634f
#define TWOLOG2E 2.8853900817779268f  // exp2(x*this) = e^{2x}

__device__ inline float readlane_f(float v, int l) {
    return __uint_as_float(__builtin_amdgcn_readlane(__float_as_uint(v), l));
}

// ---------------- Kernel A (fused): projections + exp ----------------
// 16 rows/block; thread = 8 rows x 2 h (wave = 8 rows x 128 h) -> W redundancy
// per block drops 4x -> 2x (512 -> 256 MB total W traffic; proj was L2-BW bound).
// 2-stage W prefetch + 2-stage x(LDS) prefetch, all named/static registers.
// Outputs are EXPONENTIALS: eq = exp2(s*q@Wq), ek = exp2(s*k@Wk), s = 2*log2(e).
// k-path stored transposed in [h/8][k][8] octets via LDS (octet loop unchanged).
__global__ __launch_bounds__(256, 2) void proj_kernel(const float* __restrict__ Xq,
                                                      const float* __restrict__ Xk,
                                                      const float* __restrict__ Wq,
                                                      const float* __restrict__ Wk,
                                                      float* __restrict__ EQ,
                                                      float* __restrict__ EKT,
                                                      float scale) {
    const int nb = (int)gridDim.x >> 1;
    int blk = blockIdx.x;
    const bool is_q = blk < nb;
    const float* X;
    const float* W;
    if (is_q) { X = Xq; W = Wq; }
    else      { X = Xk; W = Wk; blk -= nb; }
    const int row0 = blk * 16;

    __shared__ float xl[16][260];
    __shared__ float trans[16][260];
    const int tid = threadIdx.x;

    {
        const float4* src = (const float4*)(X + (size_t)row0 * DN);
#pragma unroll
        for (int i = 0; i < 4; ++i) {
            int idx = tid + 256 * i;
            int r = idx >> 6, c = (idx & 63) << 2;
            *(float4*)&xl[r][c] = src[idx];
        }
    }
    __syncthreads();

    const int wvid = tid >> 6;                     // wave 0..3
    const int rbase = (wvid >> 1) << 3;            // rows 0..7 or 8..15
    const int h2 = ((wvid & 1) << 7) | ((tid & 63) << 1);  // 2 h columns

    float2 acc[8];
#pragma unroll
    for (int r = 0; r < 8; ++r) acc[r] = make_float2(0.f, 0.f);

#define LOADW2(WS, D0)                                                         \
    do {                                                                       \
        _Pragma("unroll") for (int j = 0; j < 4; ++j)                          \
            WS[j] = *(const float2*)&W[(size_t)((D0) + j) * HN + h2];          \
    } while (0)

#define LOADX8(XS, D0)                                                         \
    do {                                                                       \
        _Pragma("unroll") for (int r = 0; r < 8; ++r)                          \
            XS[r] = *(const float4*)&xl[rbase + r][(D0)];                      \
    } while (0)

#define COMP2(WS, XS)                                                          \
    do {                                                                       \
        _Pragma("unroll") for (int r = 0; r < 8; ++r) {                        \
            acc[r].x = fmaf(XS[r].x, WS[0].x, acc[r].x);                       \
            acc[r].y = fmaf(XS[r].x, WS[0].y, acc[r].y);                       \
            acc[r].x = fmaf(XS[r].y, WS[1].x, acc[r].x);                       \
            acc[r].y = fmaf(XS[r].y, WS[1].y, acc[r].y);                       \
            acc[r].x = fmaf(XS[r].z, WS[2].x, acc[r].x);                       \
            acc[r].y = fmaf(XS[r].z, WS[2].y, acc[r].y);                       \
            acc[r].x = fmaf(XS[r].w, WS[3].x, acc[r].x);                       \
            acc[r].y = fmaf(XS[r].w, WS[3].y, acc[r].y);                       \
        }                                                                      \
    } while (0)

    {
        float2 w0[4], w1[4];      // static-index only (R13 lesson)
        float4 xA[8], xB[8];
        LOADX8(xA, 0);
        LOADX8(xB, 4);
        LOADW2(w0, 0);
        LOADW2(w1, 4);
        for (int d0 = 0; d0 < DN - 8; d0 += 8) {
            COMP2(w0, xA); LOADX8(xA, d0 + 8);  LOADW2(w0, d0 + 8);
            COMP2(w1, xB); LOADX8(xB, d0 + 12); LOADW2(w1, d0 + 12);
        }
        // peeled epilogue: d = 248..255
        COMP2(w0, xA);
        COMP2(w1, xB);
    }

    // apply exp2(scale * acc)
#pragma unroll
    for (int r = 0; r < 8; ++r) {
        acc[r].x = __builtin_amdgcn_exp2f(acc[r].x * scale);
        acc[r].y = __builtin_amdgcn_exp2f(acc[r].y * scale);
    }

    if (is_q) {
#pragma unroll
        for (int r = 0; r < 8; ++r)
            *(float2*)&EQ[(size_t)(row0 + rbase + r) * HN + h2] = acc[r];
    } else {
#pragma unroll
        for (int r = 0; r < 8; ++r)
            *(float2*)&trans[rbase + r][h2] = acc[r];
        __syncthreads();
        const int b = row0 >> 8, kloc0 = row0 & 255;
        float* dstb = EKT + (size_t)b * 32 * 256 * 8;
#pragma unroll
        for (int i = 0; i < 4; ++i) {
            int idx = i * 256 + tid;
            int u4 = (idx & 1) << 2;
            int kj = (idx >> 1) & 15;
            int h0 = idx >> 5;
            float4 val = *(const float4*)&trans[kj][h0 * 8 + u4];
            *(float4*)&dstb[((size_t)h0 * 256 + kloc0 + kj) * 8 + u4] = val;
        }
    }
}

// ------------- Kernel B (fused): score + masked softmax + PV ----------------
// 2 q per block -> grid 2048 -> up to 8 blocks/CU (32 waves/CU, 8/SIMD), LDS
// 11 KB, VGPR <= 64 via __launch_bounds__(256,8). R11's proven 2-deep NAMED
// k-prefetch; 2D grid keeps batches mixed per CU (len-balance, R14 lesson).
// Wave = one k-group (k = 64w+lane) for both q; q/wv in LDS (b128 broadcasts);
// PV 4-deep batched V loads; LDS O-reduce.
__global__ __launch_bounds__(256, 8) void attn_kernel(const float* __restrict__ EQ,
                                                      const float* __restrict__ EKT,
                                                      const float* __restrict__ wv,
                                                      const int* __restrict__ lens,
                                                      const float* __restrict__ V,
                                                      float* __restrict__ OUT) {
    const int b = blockIdx.y;
    const int q0 = blockIdx.x * 2;
    const int len = lens[b];

    __shared__ float eq_lds[2][256];    // 2 KB
    __shared__ float wv_lds[256];       // 1 KB
    __shared__ float part[4][2][256];   // 8 KB
    __shared__ float maxb[4][2];
    __shared__ float sumb[4][2];

    const int tid = threadIdx.x;
    const int w = tid >> 6, lane = tid & 63;

    {
        const float4* src = (const float4*)&EQ[((size_t)b * QN + q0) * HN];
        if (tid < 128) ((float4*)&eq_lds[0][0])[tid] = src[tid];  // 2 rows
        if (tid >= 192) *(float4*)&wv_lds[(tid - 192) << 2] =
            ((const float4*)wv)[tid - 192];
    }
    __syncthreads();

    const bool act = (w * 64) < len;          // wave-uniform
    float acc[2] = {0.f, 0.f};

#define WINDOW(KA, KB, H8)                                                        \
    do {                                                                          \
        float4 wa = *(const float4*)&wv_lds[(H8)];                                \
        float4 wb = *(const float4*)&wv_lds[(H8) + 4];                            \
        _Pragma("unroll") for (int qq = 0; qq < 2; ++qq) {                        \
            float4 qa = *(const float4*)&eq_lds[qq][(H8)];                        \
            float4 qb = *(const float4*)&eq_lds[qq][(H8) + 4];                    \
            float t = acc[qq];                                                    \
            t = fmaf(wa.x, __builtin_amdgcn_rcpf(fmaf(qa.x, KA.x, 1.f)), t);      \
            t = fmaf(wa.y, __builtin_amdgcn_rcpf(fmaf(qa.y, KA.y, 1.f)), t);      \
            t = fmaf(wa.z, __builtin_amdgcn_rcpf(fmaf(qa.z, KA.z, 1.f)), t);      \
            t = fmaf(wa.w, __builtin_amdgcn_rcpf(fmaf(qa.w, KA.w, 1.f)), t);      \
            t = fmaf(wb.x, __builtin_amdgcn_rcpf(fmaf(qb.x, KB.x, 1.f)), t);      \
            t = fmaf(wb.y, __builtin_amdgcn_rcpf(fmaf(qb.y, KB.y, 1.f)), t);      \
            t = fmaf(wb.z, __builtin_amdgcn_rcpf(fmaf(qb.z, KB.z, 1.f)), t);      \
            t = fmaf(wb.w, __builtin_amdgcn_rcpf(fmaf(qb.w, KB.w, 1.f)), t);      \
            acc[qq] = t;                                                          \
        }                                                                         \
    } while (0)

    if (act) {
        const float* kp = EKT + (size_t)b * (32 * 256 * 8) + (size_t)(w * 64 + lane) * 8;
        float4 ka0 = *(const float4*)&kp[0];
        float4 kb0 = *(const float4*)&kp[4];
        float4 ka1, kb1;
        for (int hw = 0; hw < 32; hw += 2) {
            const float* kp1 = kp + (size_t)(hw + 1) * 2048;
            ka1 = *(const float4*)&kp1[0];
            kb1 = *(const float4*)&kp1[4];
            WINDOW(ka0, kb0, hw * 8);
            if (hw + 2 < 32) {
                const float* kp2 = kp + (size_t)(hw + 2) * 2048;
                ka0 = *(const float4*)&kp2[0];
                kb0 = *(const float4*)&kp2[4];
            }
            WINDOW(ka1, kb1, hw * 8 + 8);
        }
    }

    const bool kvalid = (w * 64 + lane) < len;
    float xs0 = kvalid ? (-2.f * acc[0]) : -1e6f;
    float xs1 = kvalid ? (-2.f * acc[1]) : -1e6f;

    float m0 = xs0, m1 = xs1;
#pragma unroll
    for (int off = 32; off; off >>= 1) {
        m0 = fmaxf(m0, __shfl_xor(m0, off, 64));
        m1 = fmaxf(m1, __shfl_xor(m1, off, 64));
    }
    if (lane == 0) { maxb[w][0] = m0; maxb[w][1] = m1; }
    __syncthreads();
    float g0 = fmaxf(fmaxf(maxb[0][0], maxb[1][0]), fmaxf(maxb[2][0], maxb[3][0]));
    float g1 = fmaxf(fmaxf(maxb[0][1], maxb[1][1]), fmaxf(maxb[2][1], maxb[3][1]));

    float p0 = __builtin_amdgcn_exp2f((xs0 - g0) * LOG2E);
    float p1 = __builtin_amdgcn_exp2f((xs1 - g1) * LOG2E);

    float s0 = p0, s1 = p1;
#pragma unroll
    for (int off = 32; off; off >>= 1) {
        s0 += __shfl_xor(s0, off, 64);
        s1 += __shfl_xor(s1, off, 64);
    }
    if (lane == 0) { sumb[w][0] = s0; sumb[w][1] = s1; }
    __syncthreads();
    float t0 = (sumb[0][0] + sumb[1][0]) + (sumb[2][0] + sumb[3][0]);
    float t1 = (sumb[0][1] + sumb[1][1]) + (sumb[2][1] + sumb[3][1]);
    p0 *= 1.f / t0;
    p1 *= 1.f / t1;

    // PV: wave w covers its 64 k rows (clamped to len); 4-deep batched V loads
    float4 op0 = make_float4(0.f, 0.f, 0.f, 0.f);
    float4 op1 = op0;
    if (act) {
        int kmax = len - w * 64;
        if (kmax > 64) kmax = 64;
        const float* vb = V + ((size_t)b * KN + (size_t)w * 64) * DN + (lane << 2);

#define PV_STEP(KK, VV)                                                        \
    do {                                                                       \
        float b0 = readlane_f(p0, (KK));                                       \
        float b1 = readlane_f(p1, (KK));                                       \
        op0.x = fmaf(b0, VV.x, op0.x); op0.y = fmaf(b0, VV.y, op0.y);          \
        op0.z = fmaf(b0, VV.z, op0.z); op0.w = fmaf(b0, VV.w, op0.w);          \
        op1.x = fmaf(b1, VV.x, op1.x); op1.y = fmaf(b1, VV.y, op1.y);          \
        op1.z = fmaf(b1, VV.z, op1.z); op1.w = fmaf(b1, VV.w, op1.w);          \
    } while (0)

        int kk = 0;
        for (; kk + 4 <= kmax; kk += 4) {
            float4 v0 = *(const float4*)&vb[(size_t)(kk + 0) * DN];
            float4 v1 = *(const float4*)&vb[(size_t)(kk + 1) * DN];
            float4 v2 = *(const float4*)&vb[(size_t)(kk + 2) * DN];
            float4 v3 = *(const float4*)&vb[(size_t)(kk + 3) * DN];
            PV_STEP(kk + 0, v0);
            PV_STEP(kk + 1, v1);
            PV_STEP(kk + 2, v2);
            PV_STEP(kk + 3, v3);
        }
        for (; kk < kmax; ++kk) {
            float4 v0 = *(const float4*)&vb[(size_t)kk * DN];
            PV_STEP(kk, v0);
        }
    }
    {
        const int d4 = lane << 2;
        *(float4*)&part[w][0][d4] = op0;
        *(float4*)&part[w][1][d4] = op1;
    }
    __syncthreads();

    if (tid < 128) {
        const int q = tid >> 6, ln = tid & 63;
        const int d4 = ln << 2;
        float4 r0 = *(const float4*)&part[0][q][d4];
        float4 r1 = *(const float4*)&part[1][q][d4];
        float4 r2 = *(const float4*)&part[2][q][d4];
        float4 r3 = *(const float4*)&part[3][q][d4];
        float4 r = make_float4((r0.x + r1.x) + (r2.x + r3.x),
                               (r0.y + r1.y) + (r2.y + r3.y),
                               (r0.z + r1.z) + (r2.z + r3.z),
                               (r0.w + r1.w) + (r2.w + r3.w));
        *(float4*)&OUT[((size_t)b * QN + q0 + q) * DN + d4] = r;
    }
}

extern "C" void kernel_launch(void* const* d_in, const int* in_sizes, int n_in,
                              void* d_out, int out_size, void* d_ws, size_t ws_size,
                              hipStream_t stream) {
    const float* queries = (const float*)d_in[0];
    const float* keys    = (const float*)d_in[1];
    const float* values  = (const float*)d_in[2];
    const int*   lens    = (const int*)d_in[3];
    const float* Wq      = (const float*)d_in[4];
    const float* Wk      = (const float*)d_in[5];
    const float* wv      = (const float*)d_in[6];
    float* out = (float*)d_out;

    float* eq  = (float*)d_ws;                       // [B,Q,H]   4 MB (exp'd, row-major)
    float* ekT = eq + (size_t)B_ * QN * HN;          // [B,32,K,8] 4 MB (exp'd, octets)

    proj_kernel<<<(B_ * QN + B_ * KN) / 16, 256, 0, stream>>>(
        queries, keys, Wq, Wk, eq, ekT, TWOLOG2E);

    dim3 gB(QN / 2, B_);
    attn_kernel<<<gB, 256, 0, stream>>>(eq, ekT, wv, lens, values, out);
}

// Round 17
// 54.832 us; speedup vs baseline: 5.1758x; 1.0264x over previous
//
#include <hip/hip_runtime.h>

#define B_ 16
#define QN 256
#define KN 256
#define DN 256
#define HN 256

#define LOG2E 1.4426950408889634f
#define TWOLOG2E 2.8853900817779268f  // exp2(x*this) = e^{2x}

__device__ inline float readlane_f(float v, int l) {
    return __uint_as_float(__builtin_amdgcn_readlane(__float_as_uint(v), l));
}

// ---------------- Kernel A (fused): projections + exp ----------------
// (unchanged from R16: 16 rows/block; thread = 8 rows x 2 h; W redundancy 2x;
//  2-stage W + 2-stage x prefetch in named regs; exp2 epilogue; k-path stored
//  transposed in [h/8][k][8] octets via LDS.)
__global__ __launch_bounds__(256, 2) void proj_kernel(const float* __restrict__ Xq,
                                                      const float* __restrict__ Xk,
                                                      const float* __restrict__ Wq,
                                                      const float* __restrict__ Wk,
                                                      float* __restrict__ EQ,
                                                      float* __restrict__ EKT,
                                                      float scale) {
    const int nb = (int)gridDim.x >> 1;
    int blk = blockIdx.x;
    const bool is_q = blk < nb;
    const float* X;
    const float* W;
    if (is_q) { X = Xq; W = Wq; }
    else      { X = Xk; W = Wk; blk -= nb; }
    const int row0 = blk * 16;

    __shared__ float xl[16][260];
    __shared__ float trans[16][260];
    const int tid = threadIdx.x;

    {
        const float4* src = (const float4*)(X + (size_t)row0 * DN);
#pragma unroll
        for (int i = 0; i < 4; ++i) {
            int idx = tid + 256 * i;
            int r = idx >> 6, c = (idx & 63) << 2;
            *(float4*)&xl[r][c] = src[idx];
        }
    }
    __syncthreads();

    const int wvid = tid >> 6;
    const int rbase = (wvid >> 1) << 3;
    const int h2 = ((wvid & 1) << 7) | ((tid & 63) << 1);

    float2 acc[8];
#pragma unroll
    for (int r = 0; r < 8; ++r) acc[r] = make_float2(0.f, 0.f);

#define LOADW2(WS, D0)                                                         \
    do {                                                                       \
        _Pragma("unroll") for (int j = 0; j < 4; ++j)                          \
            WS[j] = *(const float2*)&W[(size_t)((D0) + j) * HN + h2];          \
    } while (0)

#define LOADX8(XS, D0)                                                         \
    do {                                                                       \
        _Pragma("unroll") for (int r = 0; r < 8; ++r)                          \
            XS[r] = *(const float4*)&xl[rbase + r][(D0)];                      \
    } while (0)

#define COMP2(WS, XS)                                                          \
    do {                                                                       \
        _Pragma("unroll") for (int r = 0; r < 8; ++r) {                        \
            acc[r].x = fmaf(XS[r].x, WS[0].x, acc[r].x);                       \
            acc[r].y = fmaf(XS[r].x, WS[0].y, acc[r].y);                       \
            acc[r].x = fmaf(XS[r].y, WS[1].x, acc[r].x);                       \
            acc[r].y = fmaf(XS[r].y, WS[1].y, acc[r].y);                       \
            acc[r].x = fmaf(XS[r].z, WS[2].x, acc[r].x);                       \
            acc[r].y = fmaf(XS[r].z, WS[2].y, acc[r].y);                       \
            acc[r].x = fmaf(XS[r].w, WS[3].x, acc[r].x);                       \
            acc[r].y = fmaf(XS[r].w, WS[3].y, acc[r].y);                       \
        }                                                                      \
    } while (0)

    {
        float2 w0[4], w1[4];
        float4 xA[8], xB[8];
        LOADX8(xA, 0);
        LOADX8(xB, 4);
        LOADW2(w0, 0);
        LOADW2(w1, 4);
        for (int d0 = 0; d0 < DN - 8; d0 += 8) {
            COMP2(w0, xA); LOADX8(xA, d0 + 8);  LOADW2(w0, d0 + 8);
            COMP2(w1, xB); LOADX8(xB, d0 + 12); LOADW2(w1, d0 + 12);
        }
        COMP2(w0, xA);
        COMP2(w1, xB);
    }

#pragma unroll
    for (int r = 0; r < 8; ++r) {
        acc[r].x = __builtin_amdgcn_exp2f(acc[r].x * scale);
        acc[r].y = __builtin_amdgcn_exp2f(acc[r].y * scale);
    }

    if (is_q) {
#pragma unroll
        for (int r = 0; r < 8; ++r)
            *(float2*)&EQ[(size_t)(row0 + rbase + r) * HN + h2] = acc[r];
    } else {
#pragma unroll
        for (int r = 0; r < 8; ++r)
            *(float2*)&trans[rbase + r][h2] = acc[r];
        __syncthreads();
        const int b = row0 >> 8, kloc0 = row0 & 255;
        float* dstb = EKT + (size_t)b * 32 * 256 * 8;
#pragma unroll
        for (int i = 0; i < 4; ++i) {
            int idx = i * 256 + tid;
            int u4 = (idx & 1) << 2;
            int kj = (idx >> 1) & 15;
            int h0 = idx >> 5;
            float4 val = *(const float4*)&trans[kj][h0 * 8 + u4];
            *(float4*)&dstb[((size_t)h0 * 256 + kloc0 + kj) * 8 + u4] = val;
        }
    }
}

// ------------- Kernel B (fused): score + masked softmax + PV ----------------
// 2 q/block, grid 2048, 8 blocks/CU. H-SPLIT score: wave w computes h-chunk
// [64w,64w+64) for ALL k-chunks (4 statically-unrolled guarded passes,
// k = 64j+lane) -> every wave always active; block score wall = 8*ceil(len/64)
// windows (was fixed 32 with ~63% waves idle). Partials combined via an 8 KB
// LDS exchange (buffer reused for the O-reduce). After the combine, wave w
// holds its k-chunk's scores -> softmax & PV unchanged from R16.
__global__ __launch_bounds__(256, 8) void attn_kernel(const float* __restrict__ EQ,
                                                      const float* __restrict__ EKT,
                                                      const float* __restrict__ wv,
                                                      const int* __restrict__ lens,
                                                      const float* __restrict__ V,
                                                      float* __restrict__ OUT) {
    const int b = blockIdx.y;
    const int q0 = blockIdx.x * 2;
    const int len = lens[b];

    __shared__ float eq_lds[2][256];    // 2 KB
    __shared__ float wv_lds[256];       // 1 KB
    __shared__ float shbuf[2048];       // 8 KB: score-partials, then O-partials
    __shared__ float maxb[4][2];
    __shared__ float sumb[4][2];

    const int tid = threadIdx.x;
    const int w = tid >> 6, lane = tid & 63;

    {
        const float4* src = (const float4*)&EQ[((size_t)b * QN + q0) * HN];
        if (tid < 128) ((float4*)&eq_lds[0][0])[tid] = src[tid];
        if (tid >= 192) *(float4*)&wv_lds[(tid - 192) << 2] =
            ((const float4*)wv)[tid - 192];
    }
    __syncthreads();

    // ---- score: wave w covers h in [64w, 64w+64); pass j covers k = 64j+lane
    float a00 = 0.f, a01 = 0.f;   // pass 0: q0, q1
    float a10 = 0.f, a11 = 0.f;
    float a20 = 0.f, a21 = 0.f;
    float a30 = 0.f, a31 = 0.f;

    const float* ekb = EKT + (size_t)b * (32 * 256 * 8) + (size_t)(8 * w) * 2048;

#define WINDOW(KA, KB, H8, A0, A1)                                               \
    do {                                                                         \
        float4 wa = *(const float4*)&wv_lds[(H8)];                               \
        float4 wb = *(const float4*)&wv_lds[(H8) + 4];                           \
        float4 qa0 = *(const float4*)&eq_lds[0][(H8)];                           \
        float4 qb0 = *(const float4*)&eq_lds[0][(H8) + 4];                       \
        float4 qa1 = *(const float4*)&eq_lds[1][(H8)];                           \
        float4 qb1 = *(const float4*)&eq_lds[1][(H8) + 4];                       \
        A0 = fmaf(wa.x, __builtin_amdgcn_rcpf(fmaf(qa0.x, KA.x, 1.f)), A0);      \
        A0 = fmaf(wa.y, __builtin_amdgcn_rcpf(fmaf(qa0.y, KA.y, 1.f)), A0);      \
        A0 = fmaf(wa.z, __builtin_amdgcn_rcpf(fmaf(qa0.z, KA.z, 1.f)), A0);      \
        A0 = fmaf(wa.w, __builtin_amdgcn_rcpf(fmaf(qa0.w, KA.w, 1.f)), A0);      \
        A0 = fmaf(wb.x, __builtin_amdgcn_rcpf(fmaf(qb0.x, KB.x, 1.f)), A0);      \
        A0 = fmaf(wb.y, __builtin_amdgcn_rcpf(fmaf(qb0.y, KB.y, 1.f)), A0);      \
        A0 = fmaf(wb.z, __builtin_amdgcn_rcpf(fmaf(qb0.z, KB.z, 1.f)), A0);      \
        A0 = fmaf(wb.w, __builtin_amdgcn_rcpf(fmaf(qb0.w, KB.w, 1.f)), A0);      \
        A1 = fmaf(wa.x, __builtin_amdgcn_rcpf(fmaf(qa1.x, KA.x, 1.f)), A1);      \
        A1 = fmaf(wa.y, __builtin_amdgcn_rcpf(fmaf(qa1.y, KA.y, 1.f)), A1);      \
        A1 = fmaf(wa.z, __builtin_amdgcn_rcpf(fmaf(qa1.z, KA.z, 1.f)), A1);      \
        A1 = fmaf(wa.w, __builtin_amdgcn_rcpf(fmaf(qa1.w, KA.w, 1.f)), A1);      \
        A1 = fmaf(wb.x, __builtin_amdgcn_rcpf(fmaf(qb1.x, KB.x, 1.f)), A1);      \
        A1 = fmaf(wb.y, __builtin_amdgcn_rcpf(fmaf(qb1.y, KB.y, 1.f)), A1);      \
        A1 = fmaf(wb.z, __builtin_amdgcn_rcpf(fmaf(qb1.z, KB.z, 1.f)), A1);      \
        A1 = fmaf(wb.w, __builtin_amdgcn_rcpf(fmaf(qb1.w, KB.w, 1.f)), A1);      \
    } while (0)

#define PASS(J, A0, A1)                                                          \
    do {                                                                         \
        if ((J) * 64 < len) {                                                    \
            const float* kp = ekb + (size_t)((J) * 64 + lane) * 8;               \
            float4 ka0 = *(const float4*)&kp[0];                                 \
            float4 kb0 = *(const float4*)&kp[4];                                 \
            float4 ka1, kb1;                                                     \
            _Pragma("unroll") for (int hw = 0; hw < 8; hw += 2) {                \
                const float* kp1 = kp + (size_t)(hw + 1) * 2048;                 \
                ka1 = *(const float4*)&kp1[0];                                   \
                kb1 = *(const float4*)&kp1[4];                                   \
                WINDOW(ka0, kb0, (w << 6) + hw * 8, A0, A1);                     \
                if (hw + 2 < 8) {                                                \
                    const float* kp2 = kp + (size_t)(hw + 2) * 2048;             \
                    ka0 = *(const float4*)&kp2[0];                               \
                    kb0 = *(const float4*)&kp2[4];                               \
                }                                                                \
                WINDOW(ka1, kb1, (w << 6) + hw * 8 + 8, A0, A1);                 \
            }                                                                    \
        }                                                                        \
    } while (0)

    PASS(0, a00, a01);
    PASS(1, a10, a11);
    PASS(2, a20, a21);
    PASS(3, a30, a31);

    // store score partials: shbuf[((w*4 + j)*2 + q)*64 + lane]
    {
        float* sp = &shbuf[(size_t)(w << 3) * 64 + lane];
        sp[0 * 64] = a00; sp[1 * 64] = a01;
        sp[2 * 64] = a10; sp[3 * 64] = a11;
        sp[4 * 64] = a20; sp[5 * 64] = a21;
        sp[6 * 64] = a30; sp[7 * 64] = a31;
    }
    __syncthreads();

    // combine: wave w sums the 4 h-chunk partials for its k-chunk (j = w)
    const bool act = (w * 64) < len;
    float sum0 = 0.f, sum1 = 0.f;
    if (act) {
#pragma unroll
        for (int hc = 0; hc < 4; ++hc) {
            sum0 += shbuf[((hc * 4 + w) * 2 + 0) * 64 + lane];
            sum1 += shbuf[((hc * 4 + w) * 2 + 1) * 64 + lane];
        }
    }
    const bool kvalid = (w * 64 + lane) < len;
    float xs0 = kvalid ? (-2.f * sum0) : -1e6f;
    float xs1 = kvalid ? (-2.f * sum1) : -1e6f;

    float m0 = xs0, m1 = xs1;
#pragma unroll
    for (int off = 32; off; off >>= 1) {
        m0 = fmaxf(m0, __shfl_xor(m0, off, 64));
        m1 = fmaxf(m1, __shfl_xor(m1, off, 64));
    }
    if (lane == 0) { maxb[w][0] = m0; maxb[w][1] = m1; }
    __syncthreads();
    float g0 = fmaxf(fmaxf(maxb[0][0], maxb[1][0]), fmaxf(maxb[2][0], maxb[3][0]));
    float g1 = fmaxf(fmaxf(maxb[0][1], maxb[1][1]), fmaxf(maxb[2][1], maxb[3][1]));

    float p0 = __builtin_amdgcn_exp2f((xs0 - g0) * LOG2E);
    float p1 = __builtin_amdgcn_exp2f((xs1 - g1) * LOG2E);

    float s0 = p0, s1 = p1;
#pragma unroll
    for (int off = 32; off; off >>= 1) {
        s0 += __shfl_xor(s0, off, 64);
        s1 += __shfl_xor(s1, off, 64);
    }
    if (lane == 0) { sumb[w][0] = s0; sumb[w][1] = s1; }
    __syncthreads();
    float t0 = (sumb[0][0] + sumb[1][0]) + (sumb[2][0] + sumb[3][0]);
    float t1 = (sumb[0][1] + sumb[1][1]) + (sumb[2][1] + sumb[3][1]);
    p0 *= 1.f / t0;
    p1 *= 1.f / t1;

    // PV: wave w covers its 64 k rows (clamped to len); 4-deep batched V loads
    float4 op0 = make_float4(0.f, 0.f, 0.f, 0.f);
    float4 op1 = op0;
    if (act) {
        int kmax = len - w * 64;
        if (kmax > 64) kmax = 64;
        const float* vb = V + ((size_t)b * KN + (size_t)w * 64) * DN + (lane << 2);

#define PV_STEP(KK, VV)                                                        \
    do {                                                                       \
        float b0 = readlane_f(p0, (KK));                                       \
        float b1 = readlane_f(p1, (KK));                                       \
        op0.x = fmaf(b0, VV.x, op0.x); op0.y = fmaf(b0, VV.y, op0.y);          \
        op0.z = fmaf(b0, VV.z, op0.z); op0.w = fmaf(b0, VV.w, op0.w);          \
        op1.x = fmaf(b1, VV.x, op1.x); op1.y = fmaf(b1, VV.y, op1.y);          \
        op1.z = fmaf(b1, VV.z, op1.z); op1.w = fmaf(b1, VV.w, op1.w);          \
    } while (0)

        int kk = 0;
        for (; kk + 4 <= kmax; kk += 4) {
            float4 v0 = *(const float4*)&vb[(size_t)(kk + 0) * DN];
            float4 v1 = *(const float4*)&vb[(size_t)(kk + 1) * DN];
            float4 v2 = *(const float4*)&vb[(size_t)(kk + 2) * DN];
            float4 v3 = *(const float4*)&vb[(size_t)(kk + 3) * DN];
            PV_STEP(kk + 0, v0);
            PV_STEP(kk + 1, v1);
            PV_STEP(kk + 2, v2);
            PV_STEP(kk + 3, v3);
        }
        for (; kk < kmax; ++kk) {
            float4 v0 = *(const float4*)&vb[(size_t)kk * DN];
            PV_STEP(kk, v0);
        }
    }
    __syncthreads();   // score-partial reads done; shbuf now reused for O-parts
    {
        const int d4 = lane << 2;
        *(float4*)&shbuf[((w << 1) + 0) * 256 + d4] = op0;
        *(float4*)&shbuf[((w << 1) + 1) * 256 + d4] = op1;
    }
    __syncthreads();

    if (tid < 128) {
        const int q = tid >> 6, ln = tid & 63;
        const int d4 = ln << 2;
        float4 r0 = *(const float4*)&shbuf[(0 * 2 + q) * 256 + d4];
        float4 r1 = *(const float4*)&shbuf[(1 * 2 + q) * 256 + d4];
        float4 r2 = *(const float4*)&shbuf[(2 * 2 + q) * 256 + d4];
        float4 r3 = *(const float4*)&shbuf[(3 * 2 + q) * 256 + d4];
        float4 r = make_float4((r0.x + r1.x) + (r2.x + r3.x),
                               (r0.y + r1.y) + (r2.y + r3.y),
                               (r0.z + r1.z) + (r2.z + r3.z),
                               (r0.w + r1.w) + (r2.w + r3.w));
        *(float4*)&OUT[((size_t)b * QN + q0 + q) * DN + d4] = r;
    }
}

extern "C" void kernel_launch(void* const* d_in, const int* in_sizes, int n_in,
                              void* d_out, int out_size, void* d_ws, size_t ws_size,
                              hipStream_t stream) {
    const float* queries = (const float*)d_in[0];
    const float* keys    = (const float*)d_in[1];
    const float* values  = (const float*)d_in[2];
    const int*   lens    = (const int*)d_in[3];
    const float* Wq      = (const float*)d_in[4];
    const float* Wk      = (const float*)d_in[5];
    const float* wv      = (const float*)d_in[6];
    float* out = (float*)d_out;

    float* eq  = (float*)d_ws;                       // [B,Q,H]   4 MB (exp'd, row-major)
    float* ekT = eq + (size_t)B_ * QN * HN;          // [B,32,K,8] 4 MB (exp'd, octets)

    proj_kernel<<<(B_ * QN + B_ * KN) / 16, 256, 0, stream>>>(
        queries, keys, Wq, Wk, eq, ekT, TWOLOG2E);

    dim3 gB(QN / 2, B_);
    attn_kernel<<<gB, 256, 0, stream>>>(eq, ekT, wv, lens, values, out);
}